// Round 14
// baseline (160.394 us; speedup 1.0000x reference)
//
#include <hip/hip_runtime.h>

typedef __attribute__((ext_vector_type(8))) short bf16x8;
typedef __attribute__((ext_vector_type(4))) float f32x4;
typedef __attribute__((ext_vector_type(16))) float f32x16;

// bank-spread XOR key: distinct for any 4 rows spaced 8 apart (3 odd => 3m
// mod 8 distinct over 4 consecutive m) -> b128 quad-alias conflicts gone.
#define KEY(r) ((((r) & 7) ^ (3 * ((r) >> 3))) & 7)

__device__ __forceinline__ unsigned short f2bf(float f) {  // RNE
    union { float f; unsigned u; } v; v.f = f;
    return (unsigned short)((v.u + 0x7FFFu + ((v.u >> 16) & 1u)) >> 16);
}
// packed round-half-up (hot path; differs from RNE only at exact ties)
__device__ __forceinline__ unsigned f2bf2_fast(float a, float b) {
    union { float f; unsigned u; } va, vb; va.f = a; vb.f = b;
    return ((va.u + 0x8000u) >> 16) | ((vb.u + 0x8000u) & 0xFFFF0000u);
}

__device__ __forceinline__ void async16(unsigned short* lds, const unsigned short* gsrc) {
    __builtin_amdgcn_global_load_lds(
        (const __attribute__((address_space(1))) void*)gsrc,
        (__attribute__((address_space(3))) void*)lds, 16, 0, 0);
}

// ---------------- Kernel 0: weight transpose + bf16 cast (swizzled) ------
__global__ __launch_bounds__(256) void k_wt(const float* __restrict__ kf,
                                            const float* __restrict__ kg,
                                            const float* __restrict__ kh,
                                            unsigned short* __restrict__ wt) {
    int n = blockIdx.x, t = threadIdx.x;
    const float* src; int stride, col;
    if (n < 32)      { src = kf; stride = 32;  col = n; }
    else if (n < 64) { src = kg; stride = 32;  col = n - 32; }
    else             { src = kh; stride = 256; col = n - 64; }
    wt[n * 256 + (((t >> 3) ^ (n & 7)) << 3) + (t & 7)] = f2bf(src[t * stride + col]);
}

// ---------------- Kernel 1: projections (unchanged, verified) ------------
__global__ __launch_bounds__(512) void k_proj(const float* __restrict__ x,
                                              const unsigned short* __restrict__ wt,
                                              unsigned short* __restrict__ f,
                                              unsigned short* __restrict__ g,
                                              unsigned short* __restrict__ hT) {
    __shared__ unsigned short xs[16384];      // 64 x 256 bf16, swizzled  32 KB
    __shared__ unsigned short ws[2][16384];   // W tile dbuf              64 KB
    int t = threadIdx.x, rb = blockIdx.x;
    int w = t >> 6, lane = t & 63, q = lane >> 4, n15 = lane & 15;
    int b = rb >> 6, nbase = (rb & 63) * 64;

#pragma unroll
    for (int i = 0; i < 8; ++i) {
        int lin = i * 512 + t, row = lin >> 6, c4 = lin & 63;
        float4 v = *(const float4*)&x[(rb * 64 + row) * 256 + c4 * 4];
        ushort4 o; o.x = f2bf(v.x); o.y = f2bf(v.y); o.z = f2bf(v.z); o.w = f2bf(v.w);
        *(ushort4*)&xs[row * 256 + (((c4 >> 1) ^ (row & 7)) << 3) + ((c4 & 1) << 2)] = o;
    }
#pragma unroll
    for (int j = 0; j < 4; ++j)
        async16(&ws[0][(j * 512 + w * 64) * 8], wt + (j * 512 + t) * 8);

    for (int ct = 0; ct < 5; ++ct) {
        int cur = ct & 1, nxt = cur ^ 1;
        __syncthreads();
        if (ct < 4) {
            const unsigned short* wsrc = wt + (ct + 1) * 16384;
#pragma unroll
            for (int j = 0; j < 4; ++j)
                async16(&ws[nxt][(j * 512 + w * 64) * 8], wsrc + (j * 512 + t) * 8);
        }
        const unsigned short* wcur = ws[cur];
        f32x4 acc[2];
        acc[0] = (f32x4){0.f, 0.f, 0.f, 0.f};
        acc[1] = (f32x4){0.f, 0.f, 0.f, 0.f};

        if (ct == 0) {                         // f,g : D[m=row][n=col]
            int rg = w & 3, cg = w >> 2;
#pragma unroll
            for (int kk = 0; kk < 8; ++kk) {
                bf16x8 a = *(const bf16x8*)&xs[(rg * 16 + n15) * 256
                                + ((((kk << 2) + q) ^ (n15 & 7)) << 3)];
#pragma unroll
                for (int nt = 0; nt < 2; ++nt) {
                    bf16x8 bw = *(const bf16x8*)&wcur[(cg * 32 + nt * 16 + n15) * 256
                                    + ((((kk << 2) + q) ^ (n15 & 7)) << 3)];
                    acc[nt] = __builtin_amdgcn_mfma_f32_16x16x32_bf16(a, bw, acc[nt], 0, 0, 0);
                }
            }
#pragma unroll
            for (int nt = 0; nt < 2; ++nt)
#pragma unroll
                for (int r = 0; r < 4; ++r) {
                    int grow = rb * 64 + rg * 16 + q * 4 + r;
                    int col = cg * 32 + nt * 16 + n15;
                    unsigned short v = f2bf(acc[nt][r]);
                    if (col < 32) f[grow * 32 + col] = v;
                    else          g[grow * 32 + (col - 32)] = v;
                }
        } else {                               // h : D[m=ch][n=row] (swapped)
            int cg = w & 3, rg = w >> 2;
#pragma unroll
            for (int kk = 0; kk < 8; ++kk) {
                bf16x8 a = *(const bf16x8*)&wcur[(cg * 16 + n15) * 256
                                + ((((kk << 2) + q) ^ (n15 & 7)) << 3)];
#pragma unroll
                for (int nt = 0; nt < 2; ++nt) {
                    bf16x8 bx = *(const bf16x8*)&xs[(rg * 32 + nt * 16 + n15) * 256
                                    + ((((kk << 2) + q) ^ (n15 & 7)) << 3)];
                    acc[nt] = __builtin_amdgcn_mfma_f32_16x16x32_bf16(a, bx, acc[nt], 0, 0, 0);
                }
            }
#pragma unroll
            for (int nt = 0; nt < 2; ++nt)
#pragma unroll
                for (int r = 0; r < 4; ++r) {
                    int ch = (ct - 1) * 64 + cg * 16 + q * 4 + r;
                    int nloc = nbase + rg * 32 + nt * 16 + n15;
                    hT[b * 1048576 + ch * 4096 + nloc] = f2bf(acc[nt][r]);
                }
        }
    }
}

// ---------------- Kernel 2: fused flash attention + residual -------------
// R13 structure (verified 78.1 us) + (1) KEY swizzle kills 4-way b128
// conflicts; (2) PV = 4 waves x (ch-block cb, key-half kh), each 64r x 64c
// x 32keys/iter with 4 accumulators -> 1 LDS read per MFMA (per-WG PV
// reads 48 -> 32 b128). Key-halves hold partial O; merged once in the
// epilogue through the dead hs buffer.
__global__ __launch_bounds__(512, 4) void k_attn(const float* __restrict__ x,
                                                 const unsigned short* __restrict__ f,
                                                 const unsigned short* __restrict__ g,
                                                 const unsigned short* __restrict__ hT,
                                                 const float* __restrict__ gamma_p,
                                                 float* __restrict__ out) {
    __shared__ unsigned short hs[2][8192];     // 128 ch x 64 keys, swizzled 32 KB
    __shared__ unsigned short pls[2][4096];    // P dbuf: 64 rows x 64 keys  16 KB
    __shared__ float lrec[64];                 // per-row 1/l
    int t = threadIdx.x, bx = blockIdx.x;
    int b = (bx >> 1) & 3;                     // one batch per XCD-pair
    int ch2 = (bx >> 3) & 1;                   // channel half (128 ch)
    int qt = ((bx & 1) << 5) | (bx >> 4);      // 64 Q-tiles of 64 rows
    int qbase = qt * 64;
    int chbase = ch2 * 128;
    int w = t >> 6, l = t & 63;
    int hi = l >> 5, l31 = l & 31;             // 32x32 roles (PV)
    int q = l >> 4, n15 = l & 15;              // 16x16 roles (S)
    const bool is_s = (w < 4);
    int cb = (w >> 1) & 1, kh = w & 1;         // PV roles (w>=4)

    // F B-frag (S-waves): B[n=qrow n15][k=8q+j], K=32 single step
    bf16x8 aFB;
    int pkey = 0;
    if (is_s) {
        aFB = *(const bf16x8*)&f[(b * 4096 + qbase + w * 16 + n15) * 32 + q * 8];
        pkey = KEY(w * 16 + n15);
    }

    // hs staging: chunk c = j*512 + t; local ch = j*64 + (t>>3); phys seg
    // t&7 holds logical seg (t&7)^KEY(ch).
    int chL0 = t >> 3, chL1 = 64 + (t >> 3);
    const unsigned short* hsrc0 = hT + b * 1048576 + (chbase + chL0) * 4096
                                + (((t & 7) ^ KEY(chL0)) << 3);
    const unsigned short* hsrc1 = hT + b * 1048576 + (chbase + chL1) * 4096
                                + (((t & 7) ^ KEY(chL1)) << 3);

    const unsigned short* gbase = g + (b * 4096 + n15) * 32 + q * 8;
    bf16x8 aG[4], aGn[4];

    f32x16 oo[4];                              // PV: (row-block rb2)*2 + ch-sub c2
#pragma unroll
    for (int a = 0; a < 4; ++a)
#pragma unroll
        for (int i = 0; i < 16; ++i) oo[a][i] = 0.f;
    float l_acc = 0.f;
    const f32x4 zero4 = (f32x4){0.f, 0.f, 0.f, 0.f};

    // PV loop-invariant swizzled offsets (ks = 2kh+{0,1}, lane half hi)
    int sA0a = 0, sA0b = 0, sA1a = 0, sA1b = 0;
    int sH0a = 0, sH0b = 0, sH1a = 0, sH1b = 0, rH0 = 0, rH1 = 0;
    if (!is_s) {
        int e0 = 4 * kh + hi, e1 = e0 + 2;
        sA0a = (e0 ^ KEY(l31)) << 3;       sA0b = (e1 ^ KEY(l31)) << 3;
        sA1a = (e0 ^ KEY(32 + l31)) << 3;  sA1b = (e1 ^ KEY(32 + l31)) << 3;
        rH0 = cb * 64 + l31; rH1 = rH0 + 32;
        sH0a = (e0 ^ KEY(rH0)) << 3;       sH0b = (e1 ^ KEY(rH0)) << 3;
        sH1a = (e0 ^ KEY(rH1)) << 3;       sH1b = (e1 ^ KEY(rH1)) << 3;
    }

    // S-step for the tile currently in aG, writing buffer `buf`
    auto s_tile = [&](int buf) {
        f32x4 sa[4];
#pragma unroll
        for (int nt = 0; nt < 4; ++nt)
            sa[nt] = __builtin_amdgcn_mfma_f32_16x16x32_bf16(aG[nt], aFB, zero4, 0, 0, 0);
#pragma unroll
        for (int nt = 0; nt < 4; ++nt)
#pragma unroll
            for (int r = 0; r < 4; ++r) {
                sa[nt][r] = __expf(sa[nt][r]);
                l_acc += sa[nt][r];
            }
        // pack & write P: key-quad kq=4nt+q, row=w*16+n15
#pragma unroll
        for (int nt = 0; nt < 4; ++nt) {
            unsigned p0 = f2bf2_fast(sa[nt][0], sa[nt][1]);
            unsigned p1 = f2bf2_fast(sa[nt][2], sa[nt][3]);
            int kq = 4 * nt + q;
            unsigned* dst = (unsigned*)&pls[buf][(w * 16 + n15) * 64]
                          + ((kq >> 1) ^ pkey) * 4 + (kq & 1) * 2;
            dst[0] = p0; dst[1] = p1;
        }
    };

    // ---- prologue: hs(0) prefetch; S(0) -> pls[0]; aG <- tile 1 ----
    async16(&hs[0][w * 512], hsrc0);
    async16(&hs[0][4096 + w * 512], hsrc1);
    if (is_s) {
#pragma unroll
        for (int nt = 0; nt < 4; ++nt)
            aG[nt] = *(const bf16x8*)&gbase[(nt * 16) * 32];
#pragma unroll
        for (int nt = 0; nt < 4; ++nt)
            aGn[nt] = *(const bf16x8*)&gbase[(64 + nt * 16) * 32];
        s_tile(0);
#pragma unroll
        for (int nt = 0; nt < 4; ++nt) aG[nt] = aGn[nt];
    }
    __syncthreads();   // publishes pls[0]; drains hs[0]

    for (int kt = 0; kt < 64; ++kt) {
        int cur = kt & 1, nxt = cur ^ 1;

        if (kt + 1 < 64) {                     // hs(kt+1) flies over this phase
            async16(&hs[nxt][w * 512], hsrc0 + (kt + 1) * 64);
            async16(&hs[nxt][4096 + w * 512], hsrc1 + (kt + 1) * 64);
        }

        if (is_s) {
            if (kt + 1 < 64) {
                int ktn = (kt + 2 < 64) ? kt + 2 : 63;
#pragma unroll
                for (int nt = 0; nt < 4; ++nt)
                    aGn[nt] = *(const bf16x8*)&gbase[(ktn * 64 + nt * 16) * 32];
                s_tile(nxt);                   // S(kt+1) from aG (= tile kt+1)
#pragma unroll
                for (int nt = 0; nt < 4; ++nt) aG[nt] = aGn[nt];
            }
        } else {
            // ---- O += P(kt).H(kt), 32 keys (kh half), 64r x 64c ----
            const unsigned short* hcur = &hs[cur][0];
            const unsigned short* pcur = &pls[cur][0];
            bf16x8 aP0 = *(const bf16x8*)&pcur[l31 * 64 + sA0a];
            bf16x8 aP1 = *(const bf16x8*)&pcur[(32 + l31) * 64 + sA1a];
            bf16x8 bH0 = *(const bf16x8*)&hcur[rH0 * 64 + sH0a];
            bf16x8 bH1 = *(const bf16x8*)&hcur[rH1 * 64 + sH1a];
            oo[0] = __builtin_amdgcn_mfma_f32_32x32x16_bf16(aP0, bH0, oo[0], 0, 0, 0);
            oo[1] = __builtin_amdgcn_mfma_f32_32x32x16_bf16(aP0, bH1, oo[1], 0, 0, 0);
            oo[2] = __builtin_amdgcn_mfma_f32_32x32x16_bf16(aP1, bH0, oo[2], 0, 0, 0);
            oo[3] = __builtin_amdgcn_mfma_f32_32x32x16_bf16(aP1, bH1, oo[3], 0, 0, 0);
            aP0 = *(const bf16x8*)&pcur[l31 * 64 + sA0b];
            aP1 = *(const bf16x8*)&pcur[(32 + l31) * 64 + sA1b];
            bH0 = *(const bf16x8*)&hcur[rH0 * 64 + sH0b];
            bH1 = *(const bf16x8*)&hcur[rH1 * 64 + sH1b];
            oo[0] = __builtin_amdgcn_mfma_f32_32x32x16_bf16(aP0, bH0, oo[0], 0, 0, 0);
            oo[1] = __builtin_amdgcn_mfma_f32_32x32x16_bf16(aP0, bH1, oo[1], 0, 0, 0);
            oo[2] = __builtin_amdgcn_mfma_f32_32x32x16_bf16(aP1, bH0, oo[2], 0, 0, 0);
            oo[3] = __builtin_amdgcn_mfma_f32_32x32x16_bf16(aP1, bH1, oo[3], 0, 0, 0);
        }

        __syncthreads();   // publish pls[nxt]; drain hs[nxt] DMA
    }

    // ---- epilogue: l reduce; key-half merge (via dead hs); store ----
    if (is_s) {
        float ps = l_acc;
        ps += __shfl_xor(ps, 16);
        ps += __shfl_xor(ps, 32);
        if (q == 0) lrec[w * 16 + n15] = 1.0f / ps;
    }
    float* mrg = (float*)&hs[0][0];            // 32 KB scratch
    if (!is_s && kh == 1) {
        int base = (cb * 64 + l) * 64;
#pragma unroll
        for (int a = 0; a < 4; ++a)
            *(f32x16*)&mrg[base + a * 16] = oo[a];
    }
    __syncthreads();
    if (!is_s && kh == 0) {
        int base = (cb * 64 + l) * 64;
#pragma unroll
        for (int a = 0; a < 4; ++a) {
            f32x16 m = *(const f32x16*)&mrg[base + a * 16];
#pragma unroll
            for (int i = 0; i < 16; ++i) oo[a][i] += m[i];
        }
        float gam = *gamma_p;
#pragma unroll
        for (int rb2 = 0; rb2 < 2; ++rb2)
#pragma unroll
            for (int c2 = 0; c2 < 2; ++c2) {
                int a = rb2 * 2 + c2;
                int ch = chbase + cb * 64 + c2 * 32 + l31;
#pragma unroll
                for (int qq = 0; qq < 4; ++qq) {
                    int r0 = rb2 * 32 + 8 * qq + 4 * hi;
                    f32x4 ri = *(const f32x4*)&lrec[r0];
#pragma unroll
                    for (int j = 0; j < 4; ++j) {
                        int idx = (b * 4096 + qbase + r0 + j) * 256 + ch;
                        out[idx] = x[idx] + gam * (oo[a][4 * qq + j] * ri[j]);
                    }
                }
            }
    }
}

// ---------------- launch ------------------------------------------------
extern "C" void kernel_launch(void* const* d_in, const int* in_sizes, int n_in,
                              void* d_out, int out_size, void* d_ws, size_t ws_size,
                              hipStream_t stream) {
    const float* x  = (const float*)d_in[0];
    const float* kf = (const float*)d_in[1];
    const float* kg = (const float*)d_in[2];
    const float* kh = (const float*)d_in[3];
    const float* gm = (const float*)d_in[4];
    float* out = (float*)d_out;

    char* ws = (char*)d_ws;
    unsigned short* wt = (unsigned short*)(ws);             // 320*256*2   = 163840 B
    unsigned short* fb = (unsigned short*)(ws + 163840);    // 16384*32*2  = 1 MiB
    unsigned short* gb = (unsigned short*)(ws + 1212416);   // 16384*32*2  = 1 MiB
    unsigned short* hT = (unsigned short*)(ws + 2260992);   // 4*256*4096*2= 8 MiB

    hipLaunchKernelGGL(k_wt,   dim3(320), dim3(256), 0, stream, kf, kg, kh, wt);
    hipLaunchKernelGGL(k_proj, dim3(256), dim3(512), 0, stream, x, wt, fb, gb, hT);
    hipLaunchKernelGGL(k_attn, dim3(512), dim3(512), 0, stream, x, fb, gb, hT, gm, out);
}